// Round 19
// baseline (133.546 us; speedup 1.0000x reference)
//
#include <hip/hip_runtime.h>

// IRNN 8-direction scan. x: [8,32,256,256] f32. Outputs (concat order):
// 0 up, 1 right, 2 down, 3 left, 4 zuoxia, 5 youxia, 6 zuoshang(==zuoxia), 7 youshang.
//
// Round-19: R18 vertical VERBATIM. Horizontal: 1024 one-wave blocks, each
// block owns 64 rows and computes BOTH w-direction scans per row (KS in
// registers): right->out1 and left->out3, 2 NT streams per wave. Theory:
// vertical's 4-stream waves hit 4.8 TB/s NT while single-stream horizontal
// hit only 3.9; multi-stream per wave = more channel-level parallelism.

namespace {
constexpr int HH = 256;
constexpr int WW = 256;
constexpr int PLANE = HH * WW;
constexpr size_t TEN = (size_t)PLANE * 256;

__device__ __forceinline__ float relu_f(float a) { return fmaxf(a, 0.0f); }

typedef float v4f __attribute__((ext_vector_type(4)));

__device__ __forceinline__ void nt_store4(float* p, const float4& v) {
    v4f t; t.x = v.x; t.y = v.y; t.z = v.z; t.w = v.w;
    __builtin_nontemporal_store(t, (v4f*)p);
}

__device__ __forceinline__ float4 ld4(const float* p) { return *(const float4*)p; }

// Forward scan rows 1..255 with depth-8 prefetch; step(r, v) consumes row r.
template <typename F>
__device__ __forceinline__ void scan_fwd(const float* xp, F&& step) {
    float4 buf[8];
    #pragma unroll
    for (int k = 0; k < 8; ++k) buf[k] = ld4(xp + (1 + k) * WW);
    #pragma unroll 1
    for (int g = 0; g < 30; ++g) {
        #pragma unroll
        for (int k = 0; k < 8; ++k) {
            const int r = 1 + 8 * g + k;
            float4 v = buf[k];
            buf[k] = ld4(xp + (r + 8) * WW);   // rows 9..248
            step(r, v);
        }
    }
    float4 t7[7];
    #pragma unroll
    for (int k = 0; k < 7; ++k) t7[k] = ld4(xp + (249 + k) * WW);
    #pragma unroll
    for (int k = 0; k < 8; ++k) step(241 + k, buf[k]);
    #pragma unroll
    for (int k = 0; k < 7; ++k) step(249 + k, t7[k]);
}

// Backward scan rows 254..0 with depth-8 prefetch; step(h, v) consumes row h.
template <typename F>
__device__ __forceinline__ void scan_bwd(const float* xp, F&& step) {
    float4 buf[8];
    #pragma unroll
    for (int k = 0; k < 8; ++k) buf[k] = ld4(xp + (254 - k) * WW);
    #pragma unroll 1
    for (int g = 0; g < 30; ++g) {
        #pragma unroll
        for (int k = 0; k < 8; ++k) {
            const int h = 254 - (8 * g + k);
            float4 v = buf[k];
            buf[k] = ld4(xp + (h - 8) * WW);   // rows 246..7
            step(h, v);
        }
    }
    float4 t7[7];
    #pragma unroll
    for (int k = 0; k < 7; ++k) t7[k] = ld4(xp + (6 - k) * WW);
    #pragma unroll
    for (int k = 0; k < 8; ++k) step(14 - k, buf[k]);
    #pragma unroll
    for (int k = 0; k < 7; ++k) step(6 - k, t7[k]);
}

// Wave-parallel RIGHT scan of one row (lane t holds cols 4t..4t+3).
// o[0]=x[0]; o[w]=relu(k*o[w-1]+x[w]).
__device__ __forceinline__ float4 wscan_right(float4 v, float k, int t) {
    float L, K, B;
    if (t == 0) {
        float o1 = relu_f(k * v.x + v.y);
        float o2 = relu_f(k * o1 + v.z);
        float o3 = relu_f(k * o2 + v.w);
        L = o3; K = 0.0f; B = o3;
    } else {
        L = 0.0f; K = k; B = v.x;
        L = fmaxf(0.0f, k * L + v.y); B = k * B + v.y; K = k * K;
        L = fmaxf(0.0f, k * L + v.z); B = k * B + v.z; K = k * K;
        L = fmaxf(0.0f, k * L + v.w); B = k * B + v.w; K = k * K;
    }
    #pragma unroll
    for (int d = 1; d < 64; d <<= 1) {
        float Lp = __shfl_up(L, d);
        float Kp = __shfl_up(K, d);
        float Bp = __shfl_up(B, d);
        if (t >= d) {
            float nL = fmaxf(L, K * Lp + B);
            float nB = K * Bp + B;
            float nK = K * Kp;
            L = nL; B = nB; K = nK;
        }
    }
    float Le = __shfl_up(L, 1);
    float Be = __shfl_up(B, 1);
    float c  = fmaxf(Le, Be);
    float4 o;
    o.x = (t == 0) ? v.x : relu_f(k * c + v.x);
    o.y = relu_f(k * o.x + v.y);
    o.z = relu_f(k * o.y + v.z);
    o.w = relu_f(k * o.z + v.w);
    return o;
}

// Wave-parallel LEFT scan: o[255]=x[255]; o[w]=relu(k*o[w+1]+x[w]).
__device__ __forceinline__ float4 wscan_left(float4 v, float k, int t) {
    float L, K, B;
    if (t == 63) {
        float o2 = relu_f(k * v.w + v.z);
        float o1 = relu_f(k * o2 + v.y);
        float o0 = relu_f(k * o1 + v.x);
        L = o0; K = 0.0f; B = o0;
    } else {
        L = 0.0f; K = k; B = v.w;
        L = fmaxf(0.0f, k * L + v.z); B = k * B + v.z; K = k * K;
        L = fmaxf(0.0f, k * L + v.y); B = k * B + v.y; K = k * K;
        L = fmaxf(0.0f, k * L + v.x); B = k * B + v.x; K = k * K;
    }
    #pragma unroll
    for (int d = 1; d < 64; d <<= 1) {
        float Lp = __shfl_down(L, d);
        float Kp = __shfl_down(K, d);
        float Bp = __shfl_down(B, d);
        if (t < 64 - d) {
            float nL = fmaxf(L, K * Lp + B);
            float nB = K * Bp + B;
            float nK = K * Kp;
            L = nL; B = nB; K = nK;
        }
    }
    float Le = __shfl_down(L, 1);
    float Be = __shfl_down(B, 1);
    float c  = fmaxf(Le, Be);
    float4 o;
    o.w = (t == 63) ? v.w : relu_f(k * c + v.w);
    o.z = relu_f(k * o.w + v.z);
    o.y = relu_f(k * o.z + v.y);
    o.x = relu_f(k * o.y + v.x);
    return o;
}
} // namespace

// ---------- vertical family, direction-fused: 512 one-wave blocks ----------
// [0,256):   fwd plane: down->out2, zuoxia->out4+out6, youxia->out5 (one x read)
// [256,512): bwd plane: up->out0, youshang->out7 (one x read)
__global__ __launch_bounds__(64) void irnn_vertical(
    const float* __restrict__ x, float* __restrict__ out,
    const float* __restrict__ wup_p, const float* __restrict__ wdn_p)
{
    const int bid = blockIdx.x;
    const int t = threadIdx.x;

    if (bid < 256) {
        const int plane = bid;
        const float wd = *wdn_p;
        const float* xp = x + (size_t)plane * PLANE + t * 4;
        float* o2 = out + 2 * TEN + (size_t)plane * PLANE + t * 4;
        float* o4 = out + 4 * TEN + (size_t)plane * PLANE + t * 4;
        float* o5 = out + 5 * TEN + (size_t)plane * PLANE + t * 4;
        float* o6 = out + 6 * TEN + (size_t)plane * PLANE + t * 4;

        float4 c2 = ld4(xp);          // h=0 pass-through for all fwd scans
        float4 c4 = c2, c5 = c2;
        nt_store4(o2, c2);
        nt_store4(o4, c4);
        nt_store4(o6, c4);
        nt_store4(o5, c5);

        scan_fwd(xp, [&](int r, float4 v) {
            // down
            c2.x = relu_f(c2.x * wd + v.x);
            c2.y = relu_f(c2.y * wd + v.y);
            c2.z = relu_f(c2.z * wd + v.z);
            c2.w = relu_f(c2.w * wd + v.w);
            nt_store4(o2 + r * WW, c2);
            // zuoxia (out[h][w] = relu(out[h-1][w-1]*wd + x[h][w]))
            {
                float pw = __shfl_up(c4.w, 1);
                float4 n;
                n.x = (t == 0) ? v.x : relu_f(pw * wd + v.x);
                n.y = relu_f(c4.x * wd + v.y);
                n.z = relu_f(c4.y * wd + v.z);
                n.w = relu_f(c4.z * wd + v.w);
                nt_store4(o4 + r * WW, n);
                nt_store4(o6 + r * WW, n);
                c4 = n;
            }
            // youxia (out[h][w] = relu(out[h-1][w+1]*wd + x[h][w]))
            {
                float nx = __shfl_down(c5.x, 1);
                float4 n;
                n.x = relu_f(c5.y * wd + v.x);
                n.y = relu_f(c5.z * wd + v.y);
                n.z = relu_f(c5.w * wd + v.z);
                n.w = (t == 63) ? v.w : relu_f(nx * wd + v.w);
                nt_store4(o5 + r * WW, n);
                c5 = n;
            }
        });
    } else {
        const int plane = bid - 256;
        const float wu = *wup_p;
        const float wd = *wdn_p;
        const float* xp = x + (size_t)plane * PLANE + t * 4;
        float* o0 = out + 0 * TEN + (size_t)plane * PLANE + t * 4;
        float* o7 = out + 7 * TEN + (size_t)plane * PLANE + t * 4;

        float4 c0 = ld4(xp + 255 * WW);   // h=255 pass-through
        float4 c7 = c0;
        nt_store4(o0 + 255 * WW, c0);
        nt_store4(o7 + 255 * WW, c7);

        scan_bwd(xp, [&](int h, float4 v) {
            // up
            c0.x = relu_f(c0.x * wu + v.x);
            c0.y = relu_f(c0.y * wu + v.y);
            c0.z = relu_f(c0.z * wu + v.z);
            c0.w = relu_f(c0.w * wu + v.w);
            nt_store4(o0 + h * WW, c0);
            // youshang (out[h][w] = relu(out[h+1][w-1]*wd + x[h][w]))
            {
                float pw = __shfl_up(c7.w, 1);
                float4 n;
                n.x = (t == 0) ? v.x : relu_f(pw * wd + v.x);
                n.y = relu_f(c7.x * wd + v.y);
                n.z = relu_f(c7.y * wd + v.z);
                n.w = relu_f(c7.z * wd + v.w);
                nt_store4(o7 + h * WW, n);
                c7 = n;
            }
        });
    }
}

// ---------- horizontal family: dual-direction KS wave scan ----------
// 1024 one-wave blocks; block owns 64 rows; per row: 1 load ->
// wscan_right -> NT out1 AND wscan_left -> NT out3 (2 streams/wave).
__global__ __launch_bounds__(64) void irnn_horizontal(
    const float* __restrict__ x, float* __restrict__ out,
    const float* __restrict__ wlf_p, const float* __restrict__ wrt_p)
{
    const int bid = blockIdx.x;
    const size_t row0 = (size_t)bid * 64;
    const int t = threadIdx.x;

    const float kr = *wrt_p;
    const float kl = *wlf_p;
    float* o1 = out + 1 * TEN + t * 4;
    float* o3 = out + 3 * TEN + t * 4;
    const float* ip = x + t * 4;

    // depth-4 register prefetch, fully static indexing (16 groups x 4)
    float4 buf[4];
    #pragma unroll
    for (int j = 0; j < 4; ++j) buf[j] = ld4(ip + (row0 + j) * WW);

    #pragma unroll 1
    for (int g = 0; g < 16; ++g) {
        #pragma unroll
        for (int j = 0; j < 4; ++j) {
            const int r = 4 * g + j;
            float4 v = buf[j];
            const int pr = (r + 4 < 64) ? (r + 4) : 63;   // clamped prefetch
            buf[j] = ld4(ip + (row0 + pr) * WW);
            nt_store4(o1 + (row0 + r) * WW, wscan_right(v, kr, t));
            nt_store4(o3 + (row0 + r) * WW, wscan_left(v, kl, t));
        }
    }
}

extern "C" void kernel_launch(void* const* d_in, const int* in_sizes, int n_in,
                              void* d_out, int out_size, void* d_ws, size_t ws_size,
                              hipStream_t stream) {
    const float* x      = (const float*)d_in[0];
    const float* w_up   = (const float*)d_in[1];
    const float* w_down = (const float*)d_in[2];
    const float* w_left = (const float*)d_in[3];
    const float* w_right= (const float*)d_in[4];
    float* out = (float*)d_out;

    hipLaunchKernelGGL(irnn_vertical, dim3(512), dim3(64), 0, stream,
                       x, out, w_up, w_down);
    hipLaunchKernelGGL(irnn_horizontal, dim3(1024), dim3(64), 0, stream,
                       x, out, w_left, w_right);
}

// Round 20
// 117.423 us; speedup vs baseline: 1.1373x; 1.1373x over previous
//
#include <hip/hip_runtime.h>

// IRNN 8-direction scan. x: [8,32,256,256] f32. Outputs (concat order):
// 0 up, 1 right, 2 down, 3 left, 4 zuoxia, 5 youxia, 6 zuoshang(==zuoxia), 7 youshang.
//
// Round-20: REVERT to R18 (champion, 117.6us). Vertical: direction-fused,
// all-NT, depth-8 prefetch, 512 one-wave blocks. Horizontal: barrier-free
// LDS-free KS wave scan, 2048 one-wave blocks (8 waves/CU), NT stores.
// This sits within ~5% of the measured NT-store floor (537 MB / ~4.8 TB/s).

namespace {
constexpr int HH = 256;
constexpr int WW = 256;
constexpr int PLANE = HH * WW;
constexpr size_t TEN = (size_t)PLANE * 256;

__device__ __forceinline__ float relu_f(float a) { return fmaxf(a, 0.0f); }

typedef float v4f __attribute__((ext_vector_type(4)));

__device__ __forceinline__ void nt_store4(float* p, const float4& v) {
    v4f t; t.x = v.x; t.y = v.y; t.z = v.z; t.w = v.w;
    __builtin_nontemporal_store(t, (v4f*)p);
}

__device__ __forceinline__ float4 ld4(const float* p) { return *(const float4*)p; }

// Forward scan rows 1..255 with depth-8 prefetch; step(r, v) consumes row r.
template <typename F>
__device__ __forceinline__ void scan_fwd(const float* xp, F&& step) {
    float4 buf[8];
    #pragma unroll
    for (int k = 0; k < 8; ++k) buf[k] = ld4(xp + (1 + k) * WW);
    #pragma unroll 1
    for (int g = 0; g < 30; ++g) {
        #pragma unroll
        for (int k = 0; k < 8; ++k) {
            const int r = 1 + 8 * g + k;
            float4 v = buf[k];
            buf[k] = ld4(xp + (r + 8) * WW);   // rows 9..248
            step(r, v);
        }
    }
    float4 t7[7];
    #pragma unroll
    for (int k = 0; k < 7; ++k) t7[k] = ld4(xp + (249 + k) * WW);
    #pragma unroll
    for (int k = 0; k < 8; ++k) step(241 + k, buf[k]);
    #pragma unroll
    for (int k = 0; k < 7; ++k) step(249 + k, t7[k]);
}

// Backward scan rows 254..0 with depth-8 prefetch; step(h, v) consumes row h.
template <typename F>
__device__ __forceinline__ void scan_bwd(const float* xp, F&& step) {
    float4 buf[8];
    #pragma unroll
    for (int k = 0; k < 8; ++k) buf[k] = ld4(xp + (254 - k) * WW);
    #pragma unroll 1
    for (int g = 0; g < 30; ++g) {
        #pragma unroll
        for (int k = 0; k < 8; ++k) {
            const int h = 254 - (8 * g + k);
            float4 v = buf[k];
            buf[k] = ld4(xp + (h - 8) * WW);   // rows 246..7
            step(h, v);
        }
    }
    float4 t7[7];
    #pragma unroll
    for (int k = 0; k < 7; ++k) t7[k] = ld4(xp + (6 - k) * WW);
    #pragma unroll
    for (int k = 0; k < 8; ++k) step(14 - k, buf[k]);
    #pragma unroll
    for (int k = 0; k < 7; ++k) step(6 - k, t7[k]);
}

// Wave-parallel RIGHT scan of one row (lane t holds cols 4t..4t+3).
// o[0]=x[0]; o[w]=relu(k*o[w-1]+x[w]).
__device__ __forceinline__ float4 wscan_right(float4 v, float k, int t) {
    float L, K, B;
    if (t == 0) {
        float o1 = relu_f(k * v.x + v.y);
        float o2 = relu_f(k * o1 + v.z);
        float o3 = relu_f(k * o2 + v.w);
        L = o3; K = 0.0f; B = o3;
    } else {
        L = 0.0f; K = k; B = v.x;
        L = fmaxf(0.0f, k * L + v.y); B = k * B + v.y; K = k * K;
        L = fmaxf(0.0f, k * L + v.z); B = k * B + v.z; K = k * K;
        L = fmaxf(0.0f, k * L + v.w); B = k * B + v.w; K = k * K;
    }
    #pragma unroll
    for (int d = 1; d < 64; d <<= 1) {
        float Lp = __shfl_up(L, d);
        float Kp = __shfl_up(K, d);
        float Bp = __shfl_up(B, d);
        if (t >= d) {
            float nL = fmaxf(L, K * Lp + B);
            float nB = K * Bp + B;
            float nK = K * Kp;
            L = nL; B = nB; K = nK;
        }
    }
    float Le = __shfl_up(L, 1);
    float Be = __shfl_up(B, 1);
    float c  = fmaxf(Le, Be);
    float4 o;
    o.x = (t == 0) ? v.x : relu_f(k * c + v.x);
    o.y = relu_f(k * o.x + v.y);
    o.z = relu_f(k * o.y + v.z);
    o.w = relu_f(k * o.z + v.w);
    return o;
}

// Wave-parallel LEFT scan: o[255]=x[255]; o[w]=relu(k*o[w+1]+x[w]).
__device__ __forceinline__ float4 wscan_left(float4 v, float k, int t) {
    float L, K, B;
    if (t == 63) {
        float o2 = relu_f(k * v.w + v.z);
        float o1 = relu_f(k * o2 + v.y);
        float o0 = relu_f(k * o1 + v.x);
        L = o0; K = 0.0f; B = o0;
    } else {
        L = 0.0f; K = k; B = v.w;
        L = fmaxf(0.0f, k * L + v.z); B = k * B + v.z; K = k * K;
        L = fmaxf(0.0f, k * L + v.y); B = k * B + v.y; K = k * K;
        L = fmaxf(0.0f, k * L + v.x); B = k * B + v.x; K = k * K;
    }
    #pragma unroll
    for (int d = 1; d < 64; d <<= 1) {
        float Lp = __shfl_down(L, d);
        float Kp = __shfl_down(K, d);
        float Bp = __shfl_down(B, d);
        if (t < 64 - d) {
            float nL = fmaxf(L, K * Lp + B);
            float nB = K * Bp + B;
            float nK = K * Kp;
            L = nL; B = nB; K = nK;
        }
    }
    float Le = __shfl_down(L, 1);
    float Be = __shfl_down(B, 1);
    float c  = fmaxf(Le, Be);
    float4 o;
    o.w = (t == 63) ? v.w : relu_f(k * c + v.w);
    o.z = relu_f(k * o.w + v.z);
    o.y = relu_f(k * o.z + v.y);
    o.x = relu_f(k * o.y + v.x);
    return o;
}
} // namespace

// ---------- vertical family, direction-fused: 512 one-wave blocks ----------
// [0,256):   fwd plane: down->out2, zuoxia->out4+out6, youxia->out5 (one x read)
// [256,512): bwd plane: up->out0, youshang->out7 (one x read)
__global__ __launch_bounds__(64) void irnn_vertical(
    const float* __restrict__ x, float* __restrict__ out,
    const float* __restrict__ wup_p, const float* __restrict__ wdn_p)
{
    const int bid = blockIdx.x;
    const int t = threadIdx.x;

    if (bid < 256) {
        const int plane = bid;
        const float wd = *wdn_p;
        const float* xp = x + (size_t)plane * PLANE + t * 4;
        float* o2 = out + 2 * TEN + (size_t)plane * PLANE + t * 4;
        float* o4 = out + 4 * TEN + (size_t)plane * PLANE + t * 4;
        float* o5 = out + 5 * TEN + (size_t)plane * PLANE + t * 4;
        float* o6 = out + 6 * TEN + (size_t)plane * PLANE + t * 4;

        float4 c2 = ld4(xp);          // h=0 pass-through for all fwd scans
        float4 c4 = c2, c5 = c2;
        nt_store4(o2, c2);
        nt_store4(o4, c4);
        nt_store4(o6, c4);
        nt_store4(o5, c5);

        scan_fwd(xp, [&](int r, float4 v) {
            // down
            c2.x = relu_f(c2.x * wd + v.x);
            c2.y = relu_f(c2.y * wd + v.y);
            c2.z = relu_f(c2.z * wd + v.z);
            c2.w = relu_f(c2.w * wd + v.w);
            nt_store4(o2 + r * WW, c2);
            // zuoxia (out[h][w] = relu(out[h-1][w-1]*wd + x[h][w]))
            {
                float pw = __shfl_up(c4.w, 1);
                float4 n;
                n.x = (t == 0) ? v.x : relu_f(pw * wd + v.x);
                n.y = relu_f(c4.x * wd + v.y);
                n.z = relu_f(c4.y * wd + v.z);
                n.w = relu_f(c4.z * wd + v.w);
                nt_store4(o4 + r * WW, n);
                nt_store4(o6 + r * WW, n);
                c4 = n;
            }
            // youxia (out[h][w] = relu(out[h-1][w+1]*wd + x[h][w]))
            {
                float nx = __shfl_down(c5.x, 1);
                float4 n;
                n.x = relu_f(c5.y * wd + v.x);
                n.y = relu_f(c5.z * wd + v.y);
                n.z = relu_f(c5.w * wd + v.z);
                n.w = (t == 63) ? v.w : relu_f(nx * wd + v.w);
                nt_store4(o5 + r * WW, n);
                c5 = n;
            }
        });
    } else {
        const int plane = bid - 256;
        const float wu = *wup_p;
        const float wd = *wdn_p;
        const float* xp = x + (size_t)plane * PLANE + t * 4;
        float* o0 = out + 0 * TEN + (size_t)plane * PLANE + t * 4;
        float* o7 = out + 7 * TEN + (size_t)plane * PLANE + t * 4;

        float4 c0 = ld4(xp + 255 * WW);   // h=255 pass-through
        float4 c7 = c0;
        nt_store4(o0 + 255 * WW, c0);
        nt_store4(o7 + 255 * WW, c7);

        scan_bwd(xp, [&](int h, float4 v) {
            // up
            c0.x = relu_f(c0.x * wu + v.x);
            c0.y = relu_f(c0.y * wu + v.y);
            c0.z = relu_f(c0.z * wu + v.z);
            c0.w = relu_f(c0.w * wu + v.w);
            nt_store4(o0 + h * WW, c0);
            // youshang (out[h][w] = relu(out[h+1][w-1]*wd + x[h][w]))
            {
                float pw = __shfl_up(c7.w, 1);
                float4 n;
                n.x = (t == 0) ? v.x : relu_f(pw * wd + v.x);
                n.y = relu_f(c7.x * wd + v.y);
                n.z = relu_f(c7.y * wd + v.z);
                n.w = relu_f(c7.z * wd + v.w);
                nt_store4(o7 + h * WW, n);
                c7 = n;
            }
        });
    }
}

// ---------- horizontal family: barrier-free KS wave scan ----------
// 2048 one-wave blocks: [0,1024) right->out1, [1024,2048) left->out3.
// Block owns 64 rows; per row: load -> KS scan in registers -> NT store.
__global__ __launch_bounds__(64) void irnn_horizontal(
    const float* __restrict__ x, float* __restrict__ out,
    const float* __restrict__ wlf_p, const float* __restrict__ wrt_p)
{
    const int bid = blockIdx.x;
    const int dir = bid >> 10;        // 0: right, 1: left
    const int rb  = bid & 1023;
    const size_t row0 = (size_t)rb * 64;
    const int t = threadIdx.x;

    const float k = dir ? *wlf_p : *wrt_p;
    float* op = out + (size_t)(dir ? 3 : 1) * TEN + t * 4;
    const float* ip = x + t * 4;

    // depth-4 register prefetch, fully static indexing (16 groups x 4)
    float4 buf[4];
    #pragma unroll
    for (int j = 0; j < 4; ++j) buf[j] = ld4(ip + (row0 + j) * WW);

    #pragma unroll 1
    for (int g = 0; g < 16; ++g) {
        #pragma unroll
        for (int j = 0; j < 4; ++j) {
            const int r = 4 * g + j;
            float4 v = buf[j];
            const int pr = (r + 4 < 64) ? (r + 4) : 63;   // clamped prefetch
            buf[j] = ld4(ip + (row0 + pr) * WW);
            float4 o = dir ? wscan_left(v, k, t) : wscan_right(v, k, t);
            nt_store4(op + (row0 + r) * WW, o);
        }
    }
}

extern "C" void kernel_launch(void* const* d_in, const int* in_sizes, int n_in,
                              void* d_out, int out_size, void* d_ws, size_t ws_size,
                              hipStream_t stream) {
    const float* x      = (const float*)d_in[0];
    const float* w_up   = (const float*)d_in[1];
    const float* w_down = (const float*)d_in[2];
    const float* w_left = (const float*)d_in[3];
    const float* w_right= (const float*)d_in[4];
    float* out = (float*)d_out;

    hipLaunchKernelGGL(irnn_vertical, dim3(512), dim3(64), 0, stream,
                       x, out, w_up, w_down);
    hipLaunchKernelGGL(irnn_horizontal, dim3(2048), dim3(64), 0, stream,
                       x, out, w_left, w_right);
}